// Round 6
// baseline (255.820 us; speedup 1.0000x reference)
//
#include <hip/hip_runtime.h>
#include <math.h>

// Problem constants (B=8, C=192, H=W=32)
#define BB 8
#define CC 192
#define LL 1024
#define RT 8192         // total rows = BB*LL
#define DI 384          // d_inner
#define DT_RANK 12
#define NS 16           // D_STATE
#define NSEG 16
#define SEGL 64

// ---------------------------------------------------------------------------
// DPP butterfly sum across a row of 16 lanes (lanes 16k..16k+15).
__device__ __forceinline__ float row_sum16(float v) {
    v += __int_as_float(__builtin_amdgcn_update_dpp(0, __float_as_int(v), 0x140, 0xF, 0xF, true));
    v += __int_as_float(__builtin_amdgcn_update_dpp(0, __float_as_int(v), 0x141, 0xF, 0xF, true));
    v += __int_as_float(__builtin_amdgcn_update_dpp(0, __float_as_int(v), 0x4E,  0xF, 0xF, true));
    v += __int_as_float(__builtin_amdgcn_update_dpp(0, __float_as_int(v), 0xB1,  0xF, 0xF, true));
    return v;
}

// ---------------------------------------------------------------------------
// K1: W2T[c',j] = sum_c in_proj_w[j,c]*proj_w[c,c'] (TRANSPOSED so gemm_xz
// can s_load contiguous per-k j-slices); bias2[j] = in_proj_w[j,:]·proj_b.
// Also: outwT[k][c] = out_w[c][k] (for gemm_out s_loads) and xdT zero-init
// (atomicAdd target of the K-split xproj GEMM; ws is poisoned every iter).
__global__ void fuse_w_kernel(const float* __restrict__ in_proj_w,
                              const float* __restrict__ proj_w,
                              const float* __restrict__ proj_b,
                              const float* __restrict__ out_w,
                              float* __restrict__ W2T, float* __restrict__ bias2,
                              float* __restrict__ outwT,
                              float* __restrict__ xdT) {
    int j = blockIdx.x;
    int cp = threadIdx.x;
    int gtid = j * CC + cp;                       // 0..147455
    for (int i = gtid; i < 44 * RT; i += 768 * CC) xdT[i] = 0.f;
    if (j < DI) outwT[j * CC + cp] = out_w[cp * DI + j];
    __shared__ float wrow[CC];
    wrow[cp] = in_proj_w[j * CC + cp];
    __syncthreads();
    float acc = 0.f;
#pragma unroll 4
    for (int c = 0; c < CC; ++c) acc = fmaf(wrow[c], proj_w[c * CC + cp], acc);
    W2T[cp * 768 + j] = acc;
    if (cp == 0) {
        float b = 0.f;
        for (int c = 0; c < CC; ++c) b = fmaf(wrow[c], proj_b[c], b);
        bias2[j] = b;
    }
}

// ---------------------------------------------------------------------------
// K2: xzT[j, row] = sum_c x[b, c, l] * W2T[c, j] + bias2[j]   (row = b*1024+l)
// R6: LDS-free streaming GEMM. R5 was LDS-pipe-bound (per-CU LDS ~3x the
// per-SIMD VALU demand). Now: wave w owns j-slice jw=j0+w*24 (wave-uniform,
// readfirstlane -> B loads become s_load from L2-resident W2T, SMEM pipe);
// lane = row; A is one coalesced per-lane global b32 per k (x is L2/L3-hot,
// 8 re-reads = ~50MB through L3 = free). No LDS, no barriers. acc[24].
// k ascending -> bitwise-identical accumulation order.
// grid (128, 8), 256 thr = 4 waves.
__global__ __launch_bounds__(256) void gemm_xz(const float* __restrict__ x,
                                               const float* __restrict__ W2T,
                                               const float* __restrict__ bias2,
                                               float* __restrict__ xzT) {
    int r0 = blockIdx.x * 64;
    int j0 = blockIdx.y * 96;
    int b  = r0 >> 10;
    int l0 = r0 & 1023;
    int tid = threadIdx.x;
    int lane = tid & 63;
    int jw = __builtin_amdgcn_readfirstlane(j0 + (tid >> 6) * 24);
    const float* bT = W2T + jw;                 // B slice base (uniform)
    const float* xb = x + b * CC * LL + l0 + lane;
    float acc[24] = {};
    for (int k = 0; k < CC; k += 8) {
        float a[8];
#pragma unroll
        for (int u = 0; u < 8; ++u) a[u] = xb[(k + u) * LL];
#pragma unroll
        for (int u = 0; u < 8; ++u) {
            const float* bp = bT + (k + u) * 768;   // uniform -> s_load_dwordx8
#pragma unroll
            for (int q = 0; q < 24; ++q)
                acc[q] = fmaf(bp[q], a[u], acc[q]);
        }
    }
    bool is_z = (j0 >= DI);
#pragma unroll
    for (int q = 0; q < 24; ++q) {
        float o = acc[q] + bias2[jw + q];
        if (is_z) o = __fdividef(o, 1.f + __expf(-o));
        xzT[(jw + q) * RT + r0 + lane] = o;
    }
}

// ---------------------------------------------------------------------------
// K3: skinny GEMM with fused causal depthwise conv (k=4) + silu in staging.
// K-split: blockIdx.y picks channel range [y*192, y*192+192); staging and
// xzT reads done once per channel; partial sums via atomicAdd into
// pre-zeroed xdT (exactly 2 contributors -> deterministic). (R3-proven.)
__global__ __launch_bounds__(512) void xproj_conv_gemm(const float* __restrict__ xzT,
                                                       const float* __restrict__ conv_w,
                                                       const float* __restrict__ conv_b,
                                                       const float* __restrict__ aw,
                                                       float* __restrict__ xcT,
                                                       float* __restrict__ xdT) {
    __shared__ float Bs[32][64];
    int col0 = blockIdx.x * 64;
    int kbase = blockIdx.y * 192;
    int tid = threadIdx.x;
    int col = tid & 63, mg = tid >> 6;          // mg wave-uniform -> scalar A loads
    int mb = mg * 6;                             // rows mb..mb+5 (44..47 discarded)
    const float* ar[6];
#pragma unroll
    for (int m = 0; m < 6; ++m) ar[m] = aw + min(mb + m, 43) * DI + kbase;
    float acc[6] = {};
    int ks = tid >> 4, c4 = (tid & 15) * 4;
    bool atL0 = ((col0 & 1023) == 0) && (c4 == 0);   // conv zero-pad boundary
    for (int k0 = 0; k0 < 192; k0 += 32) {
        int dch = kbase + k0 + ks;
        const float* src = xzT + (size_t)dch * RT + col0 + c4;
        float4 cur = *(const float4*)src;
        float4 prev = make_float4(0.f, 0.f, 0.f, 0.f);
        if (!atL0) prev = *(const float4*)(src - 4);
        float4 w4 = *(const float4*)&conv_w[dch * 4];   // w0=x w1=y w2=z w3=w
        float bb = conv_b[dch];
        float v0 = bb + w4.w * cur.x + w4.z * prev.w + w4.y * prev.z + w4.x * prev.y;
        float v1 = bb + w4.w * cur.y + w4.z * cur.x  + w4.y * prev.w + w4.x * prev.z;
        float v2 = bb + w4.w * cur.z + w4.z * cur.y  + w4.y * cur.x  + w4.x * prev.w;
        float v3 = bb + w4.w * cur.w + w4.z * cur.z  + w4.y * cur.y  + w4.x * cur.x;
        float4 o;
        o.x = __fdividef(v0, 1.f + __expf(-v0));
        o.y = __fdividef(v1, 1.f + __expf(-v1));
        o.z = __fdividef(v2, 1.f + __expf(-v2));
        o.w = __fdividef(v3, 1.f + __expf(-v3));
        *(float4*)&Bs[ks][c4] = o;
        *(float4*)&xcT[(size_t)dch * RT + col0 + c4] = o;   // own channel range
        __syncthreads();
#pragma unroll
        for (int k = 0; k < 32; ++k) {
            float bv = Bs[k][col];
#pragma unroll
            for (int m = 0; m < 6; ++m)
                acc[m] = fmaf(ar[m][k0 + k], bv, acc[m]);
        }
        __syncthreads();
    }
#pragma unroll
    for (int m = 0; m < 6; ++m)
        if (mb + m < 44)
            atomicAdd(&xdT[(mb + m) * RT + col0 + col], acc[m]);
}

// ---------------------------------------------------------------------------
// K4a: per-segment scan from h=0; dt computed inline from dtr rows of xdT.
// Emits P = exp(a*sum(dt)) (== prod(dA)), Hf = final h.
// grid (16 seg, 24 dblk, 8 b), block 256.  (R1-proven version.)
__global__ __launch_bounds__(256) void scan_part1(const float* __restrict__ xdT,
                                                  const float* __restrict__ xcT,
                                                  const float* __restrict__ dtw,
                                                  const float* __restrict__ dtb,
                                                  const float* __restrict__ A_log,
                                                  float* __restrict__ P,
                                                  float* __restrict__ Hf) {
    __shared__ float dt_s[16][20], g_s[16][20], B_s[16][20];
    __shared__ float dtr_s[12][17];
    __shared__ float dtw_s[192];
    __shared__ float dtb_s[16];
    int seg = blockIdx.x, d0 = blockIdx.y * 16, b = blockIdx.z;
    int row0 = b * LL + seg * SEGL;
    int tid = threadIdx.x;
    int lane = tid & 63;
    int n = lane & 15;
    int dl = ((tid >> 6) << 2) | (lane >> 4);
    int tdd = tid >> 4, ti = tid & 15;
    if (tid < 192) dtw_s[tid] = dtw[d0 * DT_RANK + tid];
    if (tid < 16)  dtb_s[tid] = dtb[d0 + tid];
    float a = -__expf(A_log[(d0 + dl) * NS + n]);
    float h = 0.f, sdt = 0.f;
    for (int ch = 0; ch < 4; ++ch) {
        int r = row0 + ch * 16;
        float xv = xcT[(d0 + tdd) * RT + r + ti];
        B_s[tdd][ti] = xdT[(12 + tdd) * RT + r + ti];
        if (tid < 192) dtr_s[tid >> 4][ti] = xdT[(tid >> 4) * RT + r + ti];
        __syncthreads();     // staging ready (prev chunk's preloads done)
        float acc = dtb_s[tdd];
#pragma unroll
        for (int rr = 0; rr < DT_RANK; ++rr)
            acc = fmaf(dtr_s[rr][ti], dtw_s[tdd * DT_RANK + rr], acc);
        float dtv = fmaxf(acc, 0.f) + __logf(1.f + __expf(-fabsf(acc)));
        dt_s[tdd][ti] = dtv;
        g_s[tdd][ti]  = dtv * xv;
        __syncthreads();     // dt_s/g_s ready
        float dv[16], gb[16];
#pragma unroll
        for (int q = 0; q < 4; ++q) {
            float4 d4 = *(const float4*)&dt_s[dl][q * 4];   // broadcast within row
            float4 g4 = *(const float4*)&g_s[dl][q * 4];
            float4 b4 = *(const float4*)&B_s[n][q * 4];
            dv[q * 4 + 0] = d4.x; dv[q * 4 + 1] = d4.y;
            dv[q * 4 + 2] = d4.z; dv[q * 4 + 3] = d4.w;
            gb[q * 4 + 0] = g4.x * b4.x; gb[q * 4 + 1] = g4.y * b4.y;
            gb[q * 4 + 2] = g4.z * b4.z; gb[q * 4 + 3] = g4.w * b4.w;
        }
        __syncthreads();     // preload done -> next chunk may overwrite LDS
        float eh[16];
#pragma unroll
        for (int i = 0; i < 16; ++i) eh[i] = __expf(dv[i] * a);
#pragma unroll
        for (int i = 0; i < 16; ++i) {
            sdt += dv[i];
            h = fmaf(eh[i], h, gb[i]);
        }
    }
    int idx = ((seg * BB + b) * DI + d0 + dl) * NS + n;
    P[idx] = __expf(a * sdt);
    Hf[idx] = h;
}

// ---------------------------------------------------------------------------
// K4b: rescan each segment; h_init computed in-block by folding the earlier
// segments' (P,Hf) summaries. DPP row-of-16 butterfly for the n-reduction.
// (R1-proven version.)
__global__ __launch_bounds__(256) void scan_part2(const float* __restrict__ xdT,
                                                  const float* __restrict__ xcT,
                                                  const float* __restrict__ zsT,
                                                  const float* __restrict__ dtw,
                                                  const float* __restrict__ dtb,
                                                  const float* __restrict__ P,
                                                  const float* __restrict__ Hf,
                                                  const float* __restrict__ A_log,
                                                  const float* __restrict__ Dp,
                                                  float* __restrict__ yT) {
    __shared__ float dt_s[16][20], g_s[16][20], B_s[16][20], C_s[16][20];
    __shared__ float dtr_s[12][17];
    __shared__ float dtw_s[192];
    __shared__ float dtb_s[16];
    int seg = blockIdx.x, d0 = blockIdx.y * 16, b = blockIdx.z;
    int row0 = b * LL + seg * SEGL;
    int tid = threadIdx.x;
    int lane = tid & 63;
    int n = lane & 15;
    int dl = ((tid >> 6) << 2) | (lane >> 4);
    int d = d0 + dl;
    int tdd = tid >> 4, ti = tid & 15;
    if (tid < 192) dtw_s[tid] = dtw[d0 * DT_RANK + tid];
    if (tid < 16)  dtb_s[tid] = dtb[d0 + tid];
    float a = -__expf(A_log[d * NS + n]);
    float Dpd = Dp[d];
    // h_init: fold earlier segments' summaries (coalesced loads)
    float h = 0.f;
    for (int s = 0; s < seg; ++s) {
        int off = ((s * BB + b) * DI + d) * NS + n;
        h = fmaf(P[off], h, Hf[off]);
    }
    for (int ch = 0; ch < 4; ++ch) {
        int r = row0 + ch * 16;
        // epilogue operands for the (dl,n) writer role (L1/L2-resident)
        float xr = xcT[(size_t)d * RT + r + n];
        float zr = zsT[(size_t)d * RT + r + n];
        // staging role (tdd,ti)
        float xv = xcT[(d0 + tdd) * RT + r + ti];
        B_s[tdd][ti] = xdT[(12 + tdd) * RT + r + ti];
        C_s[tdd][ti] = xdT[(28 + tdd) * RT + r + ti];
        if (tid < 192) dtr_s[tid >> 4][ti] = xdT[(tid >> 4) * RT + r + ti];
        __syncthreads();     // staging ready
        float acc = dtb_s[tdd];
#pragma unroll
        for (int rr = 0; rr < DT_RANK; ++rr)
            acc = fmaf(dtr_s[rr][ti], dtw_s[tdd * DT_RANK + rr], acc);
        float dtv = fmaxf(acc, 0.f) + __logf(1.f + __expf(-fabsf(acc)));
        dt_s[tdd][ti] = dtv;
        g_s[tdd][ti]  = dtv * xv;
        __syncthreads();     // dt_s/g_s ready
        float dv[16], gb[16], cv[16];
#pragma unroll
        for (int q = 0; q < 4; ++q) {
            float4 d4 = *(const float4*)&dt_s[dl][q * 4];
            float4 g4 = *(const float4*)&g_s[dl][q * 4];
            float4 b4 = *(const float4*)&B_s[n][q * 4];
            float4 c4 = *(const float4*)&C_s[n][q * 4];
            dv[q * 4 + 0] = d4.x; dv[q * 4 + 1] = d4.y;
            dv[q * 4 + 2] = d4.z; dv[q * 4 + 3] = d4.w;
            gb[q * 4 + 0] = g4.x * b4.x; gb[q * 4 + 1] = g4.y * b4.y;
            gb[q * 4 + 2] = g4.z * b4.z; gb[q * 4 + 3] = g4.w * b4.w;
            cv[q * 4 + 0] = c4.x; cv[q * 4 + 1] = c4.y;
            cv[q * 4 + 2] = c4.z; cv[q * 4 + 3] = c4.w;
        }
        __syncthreads();     // preload done -> next chunk may overwrite LDS
        float eh[16];
#pragma unroll
        for (int i = 0; i < 16; ++i) eh[i] = __expf(dv[i] * a);
        float yacc = 0.f;
#pragma unroll
        for (int i = 0; i < 16; ++i) {
            h = fmaf(eh[i], h, gb[i]);
            float v = row_sum16(h * cv[i]);   // sum over n within the 16-lane row
            yacc = (n == i) ? v : yacc;       // lane n keeps step i==n
        }
        yT[(size_t)d * RT + r + n] = fmaf(xr, Dpd, yacc) * zr;
    }
}

// ---------------------------------------------------------------------------
// K5: out[b, c, l] = sum_d yT[d, row] * outwT[d, c]
// R6: LDS-free streaming (same mechanism as gemm_xz). Wave w owns c-slice
// cw=c0+w*12 (uniform -> s_load from outwT); lane = row; A = coalesced
// per-lane yT b32 per k. No LDS, no barriers. k ascending (bitwise order).
// grid (128, 4), 256 thr.
__global__ __launch_bounds__(256) void gemm_out(const float* __restrict__ yT,
                                                const float* __restrict__ outwT,
                                                float* __restrict__ out) {
    int r0 = blockIdx.x * 64;
    int c0 = blockIdx.y * 48;
    int b = r0 >> 10, l0 = r0 & 1023;
    int tid = threadIdx.x;
    int lane = tid & 63;
    int cw = __builtin_amdgcn_readfirstlane(c0 + (tid >> 6) * 12);
    const float* bT = outwT + cw;
    const float* ya = yT + r0 + lane;
    float acc[12] = {};
    for (int k = 0; k < DI; k += 8) {
        float a[8];
#pragma unroll
        for (int u = 0; u < 8; ++u) a[u] = ya[(size_t)(k + u) * RT];
#pragma unroll
        for (int u = 0; u < 8; ++u) {
            const float* bp = bT + (k + u) * CC;    // uniform -> s_load
#pragma unroll
            for (int q = 0; q < 12; ++q)
                acc[q] = fmaf(bp[q], a[u], acc[q]);
        }
    }
    float* ob = out + b * CC * LL + l0 + lane;
#pragma unroll
    for (int q = 0; q < 12; ++q)
        ob[(cw + q) * LL] = acc[q];
}

// ---------------------------------------------------------------------------
extern "C" void kernel_launch(void* const* d_in, const int* in_sizes, int n_in,
                              void* d_out, int out_size, void* d_ws, size_t ws_size,
                              hipStream_t stream) {
    const float* x         = (const float*)d_in[0];
    const float* proj_w    = (const float*)d_in[1];
    const float* proj_b    = (const float*)d_in[2];
    const float* in_proj_w = (const float*)d_in[3];
    const float* conv_w    = (const float*)d_in[4];
    const float* conv_b    = (const float*)d_in[5];
    const float* xproj_w   = (const float*)d_in[6];
    const float* dtproj_w  = (const float*)d_in[7];
    const float* dtproj_b  = (const float*)d_in[8];
    const float* A_log     = (const float*)d_in[9];
    const float* Dp        = (const float*)d_in[10];
    const float* out_w     = (const float*)d_in[11];
    float* out = (float*)d_out;

    float* ws    = (float*)d_ws;
    float* W2T   = ws;                    // 147456 (transposed: [c][j])
    float* bias2 = W2T + 147456;          // 768
    float* xzT   = bias2 + 768;           // 768*8192 = 6291456 (x raw, z silu'd)
    float* xcT   = xzT + 6291456;         // 3145728
    float* yT    = xcT + 3145728;         // 3145728
    float* xdT   = yT + 3145728;          // 44*8192 = 360448 (0-11 dtr, 12-27 B, 28-43 C)
    float* P     = xdT + 360448;          // 786432
    float* Hf    = P + 786432;            // 786432
    float* outwT = Hf + 786432;           // 384*192 = 73728 (transposed: [k][c])
    float* zsT   = xzT + DI * RT;         // z half, silu applied by gemm_xz epilogue

    fuse_w_kernel<<<768, 192, 0, stream>>>(in_proj_w, proj_w, proj_b, out_w,
                                           W2T, bias2, outwT, xdT);
    gemm_xz<<<dim3(128, 8), 256, 0, stream>>>(x, W2T, bias2, xzT);
    xproj_conv_gemm<<<dim3(128, 2), 512, 0, stream>>>(xzT, conv_w, conv_b,
                                                      xproj_w, xcT, xdT);
    scan_part1<<<dim3(16, 24, 8), 256, 0, stream>>>(xdT, xcT, dtproj_w, dtproj_b,
                                                    A_log, P, Hf);
    scan_part2<<<dim3(16, 24, 8), 256, 0, stream>>>(xdT, xcT, zsT, dtproj_w, dtproj_b,
                                                    P, Hf, A_log, Dp, yT);
    gemm_out<<<dim3(128, 4), 256, 0, stream>>>(yT, outwT, out);
}

// Round 7
// 209.977 us; speedup vs baseline: 1.2183x; 1.2183x over previous
//
#include <hip/hip_runtime.h>
#include <math.h>

// Problem constants (B=8, C=192, H=W=32)
#define BB 8
#define CC 192
#define LL 1024
#define RT 8192         // total rows = BB*LL
#define DI 384          // d_inner
#define DT_RANK 12
#define NS 16           // D_STATE
#define NSEG 16
#define SEGL 64

typedef __attribute__((ext_vector_type(8))) short bf16x8;   // 8 bf16 (4 VGPRs)
typedef __attribute__((ext_vector_type(4))) float f32x4;

// RNE float->bf16 and back, manual (no header dependency)
__device__ __forceinline__ unsigned short f2bf(float f) {
    unsigned u = __float_as_uint(f);
    unsigned r = (u + 0x7FFFu + ((u >> 16) & 1u)) >> 16;
    return (unsigned short)r;
}
__device__ __forceinline__ float bf2f(unsigned short h) {
    return __uint_as_float(((unsigned)h) << 16);
}

// ---------------------------------------------------------------------------
// async global->LDS, 16B per lane. Dest must be linear in lane id within the
// wave (HW uses wave-uniform base + lane*16).
__device__ __forceinline__ void gload_lds16(const float* g, float* l) {
    __builtin_amdgcn_global_load_lds(
        (const __attribute__((address_space(1))) void*)(g),
        (__attribute__((address_space(3))) void*)(l),
        16, 0, 0);
}

// ---------------------------------------------------------------------------
// DPP butterfly sum across a row of 16 lanes (lanes 16k..16k+15).
__device__ __forceinline__ float row_sum16(float v) {
    v += __int_as_float(__builtin_amdgcn_update_dpp(0, __float_as_int(v), 0x140, 0xF, 0xF, true));
    v += __int_as_float(__builtin_amdgcn_update_dpp(0, __float_as_int(v), 0x141, 0xF, 0xF, true));
    v += __int_as_float(__builtin_amdgcn_update_dpp(0, __float_as_int(v), 0x4E,  0xF, 0xF, true));
    v += __int_as_float(__builtin_amdgcn_update_dpp(0, __float_as_int(v), 0xB1,  0xF, 0xF, true));
    return v;
}

// ---------------------------------------------------------------------------
// K1: W2[j,c'] = sum_c in_proj_w[j,c]*proj_w[c,c'], emitted as SPLIT bf16
// planes W2hi/W2lo (w = hi + lo, |lo| <= 2^-9 |w|) for the MFMA gemm_xz.
// bias2[j] = in_proj_w[j,:]·proj_b. Also zero-inits xdT (atomicAdd target
// of the K-split xproj GEMM; ws is poisoned every iteration).
__global__ void fuse_w_kernel(const float* __restrict__ in_proj_w,
                              const float* __restrict__ proj_w,
                              const float* __restrict__ proj_b,
                              unsigned short* __restrict__ W2hi,
                              unsigned short* __restrict__ W2lo,
                              float* __restrict__ bias2,
                              float* __restrict__ xdT) {
    int j = blockIdx.x;
    int cp = threadIdx.x;
    int gtid = j * CC + cp;                       // 0..147455
    for (int i = gtid; i < 44 * RT; i += 768 * CC) xdT[i] = 0.f;
    __shared__ float wrow[CC];
    wrow[cp] = in_proj_w[j * CC + cp];
    __syncthreads();
    float acc = 0.f;
#pragma unroll 4
    for (int c = 0; c < CC; ++c) acc = fmaf(wrow[c], proj_w[c * CC + cp], acc);
    unsigned short h = f2bf(acc);
    W2hi[j * CC + cp] = h;
    W2lo[j * CC + cp] = f2bf(acc - bf2f(h));
    if (cp == 0) {
        float b = 0.f;
        for (int c = 0; c < CC; ++c) b = fmaf(wrow[c], proj_b[c], b);
        bias2[j] = b;
    }
}

// ---------------------------------------------------------------------------
// K2: xzT[j, row] = sum_c x[b,c,l]*W2[j,c] + bias2[j]  via split-bf16 MFMA.
// R7: fp32 VALU path was operand-delivery-bound at ~43us regardless of
// LDS (R5) or SMEM (R6) sourcing. Split trick: D = Whi*Xhi + Whi*Xlo +
// Wlo*Xhi (3x mfma_f32_16x16x32_bf16) leaves only ~2^-18-relative error.
// Tile 64j x 64row, 4 waves; wave w owns j-slice jw=j0+w*16, all 4 row
// sub-tiles. x staged per 32-k step as hi/lo bf16 in B-fragment order:
// LDS [kb(4)][col(64)][e(8)] so lane l's ds_read_b128 at
// ((l>>4)*64 + rt*16 + (l&15))*8 yields B[k=8*(l>>4)+e][n=rt*16+(l&15)].
// A-frags straight from L2-resident W2hi/lo. C/D mapping (m89-verified):
// col=lane&15, row=(lane>>4)*4+reg. grid (128,12), 256 thr, 8KB LDS.
__global__ __launch_bounds__(256) void gemm_xz(const float* __restrict__ x,
                                               const unsigned short* __restrict__ W2hi,
                                               const unsigned short* __restrict__ W2lo,
                                               const float* __restrict__ bias2,
                                               float* __restrict__ xzT) {
    __shared__ unsigned short xhi[2048];   // [kb][col][e] 4KB
    __shared__ unsigned short xlo[2048];
    int r0 = blockIdx.x * 64;
    int j0 = blockIdx.y * 64;
    int b  = r0 >> 10;
    int l0 = r0 & 1023;
    int tid = threadIdx.x;
    int lane = tid & 63;
    int wid = tid >> 6;          // wave id = staging kb
    int jw = j0 + wid * 16;
    const float* xb = x + b * CC * LL + l0 + lane;   // staging col = lane
    f32x4 z4 = {0.f, 0.f, 0.f, 0.f};
    f32x4 acc[4] = {z4, z4, z4, z4};
    int arow = jw + (lane & 15);           // A fragment row (j)
    int akb  = (lane >> 4) * 8;            // A fragment k sub-block
    for (int ks = 0; ks < 6; ++ks) {
        int k0 = ks * 32;
        // ---- stage x[k0+kb*8+e][l0+col] -> hi/lo bf16 in frag order
        float v[8];
#pragma unroll
        for (int e = 0; e < 8; ++e) v[e] = xb[(k0 + wid * 8 + e) * LL];
        union U8 { unsigned short u[8]; bf16x8 v8; } hv, lv;
#pragma unroll
        for (int e = 0; e < 8; ++e) {
            unsigned short h = f2bf(v[e]);
            hv.u[e] = h;
            lv.u[e] = f2bf(v[e] - bf2f(h));
        }
        *(bf16x8*)&xhi[(wid * 64 + lane) * 8] = hv.v8;
        *(bf16x8*)&xlo[(wid * 64 + lane) * 8] = lv.v8;
        __syncthreads();
        // ---- A fragments (hi/lo) for this k-step
        int aoff = arow * CC + k0 + akb;
        bf16x8 ah = *(const bf16x8*)&W2hi[aoff];
        bf16x8 al = *(const bf16x8*)&W2lo[aoff];
        // ---- 4 row sub-tiles x 3 split-mfma
#pragma unroll
        for (int rt = 0; rt < 4; ++rt) {
            int boff = ((lane >> 4) * 64 + rt * 16 + (lane & 15)) * 8;
            bf16x8 bh = *(const bf16x8*)&xhi[boff];
            bf16x8 bl = *(const bf16x8*)&xlo[boff];
            acc[rt] = __builtin_amdgcn_mfma_f32_16x16x32_bf16(ah, bh, acc[rt], 0, 0, 0);
            acc[rt] = __builtin_amdgcn_mfma_f32_16x16x32_bf16(ah, bl, acc[rt], 0, 0, 0);
            acc[rt] = __builtin_amdgcn_mfma_f32_16x16x32_bf16(al, bh, acc[rt], 0, 0, 0);
        }
        __syncthreads();
    }
    bool is_z = (j0 >= DI);
#pragma unroll
    for (int rt = 0; rt < 4; ++rt) {
        int rbase = r0 + rt * 16 + (lane & 15);
#pragma unroll
        for (int reg = 0; reg < 4; ++reg) {
            int j = jw + (lane >> 4) * 4 + reg;
            float o = acc[rt][reg] + bias2[j];
            if (is_z) o = __fdividef(o, 1.f + __expf(-o));
            xzT[j * RT + rbase] = o;
        }
    }
}

// ---------------------------------------------------------------------------
// K3: skinny GEMM with fused causal depthwise conv (k=4) + silu in staging.
// K-split: blockIdx.y picks channel range [y*192, y*192+192); staging and
// xzT reads done once per channel; partial sums via atomicAdd into
// pre-zeroed xdT (exactly 2 contributors -> deterministic). (R3-proven.)
__global__ __launch_bounds__(512) void xproj_conv_gemm(const float* __restrict__ xzT,
                                                       const float* __restrict__ conv_w,
                                                       const float* __restrict__ conv_b,
                                                       const float* __restrict__ aw,
                                                       float* __restrict__ xcT,
                                                       float* __restrict__ xdT) {
    __shared__ float Bs[32][64];
    int col0 = blockIdx.x * 64;
    int kbase = blockIdx.y * 192;
    int tid = threadIdx.x;
    int col = tid & 63, mg = tid >> 6;          // mg wave-uniform -> scalar A loads
    int mb = mg * 6;                             // rows mb..mb+5 (44..47 discarded)
    const float* ar[6];
#pragma unroll
    for (int m = 0; m < 6; ++m) ar[m] = aw + min(mb + m, 43) * DI + kbase;
    float acc[6] = {};
    int ks = tid >> 4, c4 = (tid & 15) * 4;
    bool atL0 = ((col0 & 1023) == 0) && (c4 == 0);   // conv zero-pad boundary
    for (int k0 = 0; k0 < 192; k0 += 32) {
        int dch = kbase + k0 + ks;
        const float* src = xzT + (size_t)dch * RT + col0 + c4;
        float4 cur = *(const float4*)src;
        float4 prev = make_float4(0.f, 0.f, 0.f, 0.f);
        if (!atL0) prev = *(const float4*)(src - 4);
        float4 w4 = *(const float4*)&conv_w[dch * 4];   // w0=x w1=y w2=z w3=w
        float bb = conv_b[dch];
        float v0 = bb + w4.w * cur.x + w4.z * prev.w + w4.y * prev.z + w4.x * prev.y;
        float v1 = bb + w4.w * cur.y + w4.z * cur.x  + w4.y * prev.w + w4.x * prev.z;
        float v2 = bb + w4.w * cur.z + w4.z * cur.y  + w4.y * cur.x  + w4.x * prev.w;
        float v3 = bb + w4.w * cur.w + w4.z * cur.z  + w4.y * cur.y  + w4.x * cur.x;
        float4 o;
        o.x = __fdividef(v0, 1.f + __expf(-v0));
        o.y = __fdividef(v1, 1.f + __expf(-v1));
        o.z = __fdividef(v2, 1.f + __expf(-v2));
        o.w = __fdividef(v3, 1.f + __expf(-v3));
        *(float4*)&Bs[ks][c4] = o;
        *(float4*)&xcT[(size_t)dch * RT + col0 + c4] = o;   // own channel range
        __syncthreads();
#pragma unroll
        for (int k = 0; k < 32; ++k) {
            float bv = Bs[k][col];
#pragma unroll
            for (int m = 0; m < 6; ++m)
                acc[m] = fmaf(ar[m][k0 + k], bv, acc[m]);
        }
        __syncthreads();
    }
#pragma unroll
    for (int m = 0; m < 6; ++m)
        if (mb + m < 44)
            atomicAdd(&xdT[(mb + m) * RT + col0 + col], acc[m]);
}

// ---------------------------------------------------------------------------
// K4a: per-segment scan from h=0; dt computed inline from dtr rows of xdT.
// Emits P = exp(a*sum(dt)) (== prod(dA)), Hf = final h.
// grid (16 seg, 24 dblk, 8 b), block 256.  (R1-proven version.)
__global__ __launch_bounds__(256) void scan_part1(const float* __restrict__ xdT,
                                                  const float* __restrict__ xcT,
                                                  const float* __restrict__ dtw,
                                                  const float* __restrict__ dtb,
                                                  const float* __restrict__ A_log,
                                                  float* __restrict__ P,
                                                  float* __restrict__ Hf) {
    __shared__ float dt_s[16][20], g_s[16][20], B_s[16][20];
    __shared__ float dtr_s[12][17];
    __shared__ float dtw_s[192];
    __shared__ float dtb_s[16];
    int seg = blockIdx.x, d0 = blockIdx.y * 16, b = blockIdx.z;
    int row0 = b * LL + seg * SEGL;
    int tid = threadIdx.x;
    int lane = tid & 63;
    int n = lane & 15;
    int dl = ((tid >> 6) << 2) | (lane >> 4);
    int tdd = tid >> 4, ti = tid & 15;
    if (tid < 192) dtw_s[tid] = dtw[d0 * DT_RANK + tid];
    if (tid < 16)  dtb_s[tid] = dtb[d0 + tid];
    float a = -__expf(A_log[(d0 + dl) * NS + n]);
    float h = 0.f, sdt = 0.f;
    for (int ch = 0; ch < 4; ++ch) {
        int r = row0 + ch * 16;
        float xv = xcT[(d0 + tdd) * RT + r + ti];
        B_s[tdd][ti] = xdT[(12 + tdd) * RT + r + ti];
        if (tid < 192) dtr_s[tid >> 4][ti] = xdT[(tid >> 4) * RT + r + ti];
        __syncthreads();     // staging ready (prev chunk's preloads done)
        float acc = dtb_s[tdd];
#pragma unroll
        for (int rr = 0; rr < DT_RANK; ++rr)
            acc = fmaf(dtr_s[rr][ti], dtw_s[tdd * DT_RANK + rr], acc);
        float dtv = fmaxf(acc, 0.f) + __logf(1.f + __expf(-fabsf(acc)));
        dt_s[tdd][ti] = dtv;
        g_s[tdd][ti]  = dtv * xv;
        __syncthreads();     // dt_s/g_s ready
        float dv[16], gb[16];
#pragma unroll
        for (int q = 0; q < 4; ++q) {
            float4 d4 = *(const float4*)&dt_s[dl][q * 4];   // broadcast within row
            float4 g4 = *(const float4*)&g_s[dl][q * 4];
            float4 b4 = *(const float4*)&B_s[n][q * 4];
            dv[q * 4 + 0] = d4.x; dv[q * 4 + 1] = d4.y;
            dv[q * 4 + 2] = d4.z; dv[q * 4 + 3] = d4.w;
            gb[q * 4 + 0] = g4.x * b4.x; gb[q * 4 + 1] = g4.y * b4.y;
            gb[q * 4 + 2] = g4.z * b4.z; gb[q * 4 + 3] = g4.w * b4.w;
        }
        __syncthreads();     // preload done -> next chunk may overwrite LDS
        float eh[16];
#pragma unroll
        for (int i = 0; i < 16; ++i) eh[i] = __expf(dv[i] * a);
#pragma unroll
        for (int i = 0; i < 16; ++i) {
            sdt += dv[i];
            h = fmaf(eh[i], h, gb[i]);
        }
    }
    int idx = ((seg * BB + b) * DI + d0 + dl) * NS + n;
    P[idx] = __expf(a * sdt);
    Hf[idx] = h;
}

// ---------------------------------------------------------------------------
// K4b: rescan each segment; h_init computed in-block by folding the earlier
// segments' (P,Hf) summaries. DPP row-of-16 butterfly for the n-reduction.
// (R1-proven version.)
__global__ __launch_bounds__(256) void scan_part2(const float* __restrict__ xdT,
                                                  const float* __restrict__ xcT,
                                                  const float* __restrict__ zsT,
                                                  const float* __restrict__ dtw,
                                                  const float* __restrict__ dtb,
                                                  const float* __restrict__ P,
                                                  const float* __restrict__ Hf,
                                                  const float* __restrict__ A_log,
                                                  const float* __restrict__ Dp,
                                                  float* __restrict__ yT) {
    __shared__ float dt_s[16][20], g_s[16][20], B_s[16][20], C_s[16][20];
    __shared__ float dtr_s[12][17];
    __shared__ float dtw_s[192];
    __shared__ float dtb_s[16];
    int seg = blockIdx.x, d0 = blockIdx.y * 16, b = blockIdx.z;
    int row0 = b * LL + seg * SEGL;
    int tid = threadIdx.x;
    int lane = tid & 63;
    int n = lane & 15;
    int dl = ((tid >> 6) << 2) | (lane >> 4);
    int d = d0 + dl;
    int tdd = tid >> 4, ti = tid & 15;
    if (tid < 192) dtw_s[tid] = dtw[d0 * DT_RANK + tid];
    if (tid < 16)  dtb_s[tid] = dtb[d0 + tid];
    float a = -__expf(A_log[d * NS + n]);
    float Dpd = Dp[d];
    // h_init: fold earlier segments' summaries (coalesced loads)
    float h = 0.f;
    for (int s = 0; s < seg; ++s) {
        int off = ((s * BB + b) * DI + d) * NS + n;
        h = fmaf(P[off], h, Hf[off]);
    }
    for (int ch = 0; ch < 4; ++ch) {
        int r = row0 + ch * 16;
        // epilogue operands for the (dl,n) writer role (L1/L2-resident)
        float xr = xcT[(size_t)d * RT + r + n];
        float zr = zsT[(size_t)d * RT + r + n];
        // staging role (tdd,ti)
        float xv = xcT[(d0 + tdd) * RT + r + ti];
        B_s[tdd][ti] = xdT[(12 + tdd) * RT + r + ti];
        C_s[tdd][ti] = xdT[(28 + tdd) * RT + r + ti];
        if (tid < 192) dtr_s[tid >> 4][ti] = xdT[(tid >> 4) * RT + r + ti];
        __syncthreads();     // staging ready
        float acc = dtb_s[tdd];
#pragma unroll
        for (int rr = 0; rr < DT_RANK; ++rr)
            acc = fmaf(dtr_s[rr][ti], dtw_s[tdd * DT_RANK + rr], acc);
        float dtv = fmaxf(acc, 0.f) + __logf(1.f + __expf(-fabsf(acc)));
        dt_s[tdd][ti] = dtv;
        g_s[tdd][ti]  = dtv * xv;
        __syncthreads();     // dt_s/g_s ready
        float dv[16], gb[16], cv[16];
#pragma unroll
        for (int q = 0; q < 4; ++q) {
            float4 d4 = *(const float4*)&dt_s[dl][q * 4];
            float4 g4 = *(const float4*)&g_s[dl][q * 4];
            float4 b4 = *(const float4*)&B_s[n][q * 4];
            float4 c4 = *(const float4*)&C_s[n][q * 4];
            dv[q * 4 + 0] = d4.x; dv[q * 4 + 1] = d4.y;
            dv[q * 4 + 2] = d4.z; dv[q * 4 + 3] = d4.w;
            gb[q * 4 + 0] = g4.x * b4.x; gb[q * 4 + 1] = g4.y * b4.y;
            gb[q * 4 + 2] = g4.z * b4.z; gb[q * 4 + 3] = g4.w * b4.w;
            cv[q * 4 + 0] = c4.x; cv[q * 4 + 1] = c4.y;
            cv[q * 4 + 2] = c4.z; cv[q * 4 + 3] = c4.w;
        }
        __syncthreads();     // preload done -> next chunk may overwrite LDS
        float eh[16];
#pragma unroll
        for (int i = 0; i < 16; ++i) eh[i] = __expf(dv[i] * a);
        float yacc = 0.f;
#pragma unroll
        for (int i = 0; i < 16; ++i) {
            h = fmaf(eh[i], h, gb[i]);
            float v = row_sum16(h * cv[i]);   // sum over n within the 16-lane row
            yacc = (n == i) ? v : yacc;       // lane n keeps step i==n
        }
        yT[(size_t)d * RT + r + n] = fmaf(xr, Dpd, yacc) * zr;
    }
}

// ---------------------------------------------------------------------------
// K5: out[b, c, l] = sum_d yT[d, row] * out_w[c, d]
// 64x64 tile, 4x4 microtile, 256 threads. grid (128, 3).
// As unpadded [16][64] (staging linear in tid) staged via global_load_lds.
// (R5-proven version.)
__global__ __launch_bounds__(256) void gemm_out(const float* __restrict__ yT,
                                                const float* __restrict__ out_w,
                                                float* __restrict__ out) {
    __shared__ float As[16][64];  // [k][row], linear
    __shared__ float Bs[16][68];  // [k][c]
    int r0 = blockIdx.x * 64;
    int c0 = blockIdx.y * 64;
    int b = r0 >> 10, l0 = r0 & 1023;
    int tid = threadIdx.x;
    int tx = tid & 15;   // -> row
    int ty = tid >> 4;   // -> c
    float acc[4][4] = {};  // [cc][rc]
    for (int k0 = 0; k0 < DI; k0 += 16) {
        {   // A: yT[k0+k, r0+r..] -> As linear (k*64 + r4 == tid*4)
            gload_lds16(&yT[(k0 + (tid >> 4)) * RT + r0 + (tid & 15) * 4],
                        ((float*)As) + tid * 4);
        }
        {   // B: out_w[c0+c, k0+kc..] -> Bs[kc][c]
            int c = tid >> 2, kc = (tid & 3) * 4;
            float4 v = *(const float4*)&out_w[(c0 + c) * DI + k0 + kc];
            Bs[kc + 0][c] = v.x; Bs[kc + 1][c] = v.y;
            Bs[kc + 2][c] = v.z; Bs[kc + 3][c] = v.w;
        }
        __syncthreads();
#pragma unroll
        for (int k = 0; k < 16; ++k) {
            float4 av = *(const float4*)&As[k][tx * 4];
            float4 bv = *(const float4*)&Bs[k][ty * 4];
            acc[0][0] = fmaf(bv.x, av.x, acc[0][0]);
            acc[0][1] = fmaf(bv.x, av.y, acc[0][1]);
            acc[0][2] = fmaf(bv.x, av.z, acc[0][2]);
            acc[0][3] = fmaf(bv.x, av.w, acc[0][3]);
            acc[1][0] = fmaf(bv.y, av.x, acc[1][0]);
            acc[1][1] = fmaf(bv.y, av.y, acc[1][1]);
            acc[1][2] = fmaf(bv.y, av.z, acc[1][2]);
            acc[1][3] = fmaf(bv.y, av.w, acc[1][3]);
            acc[2][0] = fmaf(bv.z, av.x, acc[2][0]);
            acc[2][1] = fmaf(bv.z, av.y, acc[2][1]);
            acc[2][2] = fmaf(bv.z, av.z, acc[2][2]);
            acc[2][3] = fmaf(bv.z, av.w, acc[2][3]);
            acc[3][0] = fmaf(bv.w, av.x, acc[3][0]);
            acc[3][1] = fmaf(bv.w, av.y, acc[3][1]);
            acc[3][2] = fmaf(bv.w, av.z, acc[3][2]);
            acc[3][3] = fmaf(bv.w, av.w, acc[3][3]);
        }
        __syncthreads();
    }
    float* ob = out + b * CC * LL;
#pragma unroll
    for (int ic = 0; ic < 4; ++ic) {
        float4 o;
        o.x = acc[ic][0]; o.y = acc[ic][1]; o.z = acc[ic][2]; o.w = acc[ic][3];
        *(float4*)&ob[(c0 + ty * 4 + ic) * LL + l0 + tx * 4] = o;
    }
}

// ---------------------------------------------------------------------------
extern "C" void kernel_launch(void* const* d_in, const int* in_sizes, int n_in,
                              void* d_out, int out_size, void* d_ws, size_t ws_size,
                              hipStream_t stream) {
    const float* x         = (const float*)d_in[0];
    const float* proj_w    = (const float*)d_in[1];
    const float* proj_b    = (const float*)d_in[2];
    const float* in_proj_w = (const float*)d_in[3];
    const float* conv_w    = (const float*)d_in[4];
    const float* conv_b    = (const float*)d_in[5];
    const float* xproj_w   = (const float*)d_in[6];
    const float* dtproj_w  = (const float*)d_in[7];
    const float* dtproj_b  = (const float*)d_in[8];
    const float* A_log     = (const float*)d_in[9];
    const float* Dp        = (const float*)d_in[10];
    const float* out_w     = (const float*)d_in[11];
    float* out = (float*)d_out;

    float* ws    = (float*)d_ws;
    unsigned short* W2hi = (unsigned short*)ws;          // 147456 bf16 = 73728 f32 slots
    unsigned short* W2lo = (unsigned short*)(ws + 73728);// 147456 bf16 = 73728 f32 slots
    float* bias2 = ws + 147456;           // 768
    float* xzT   = bias2 + 768;           // 768*8192 = 6291456 (x raw, z silu'd)
    float* xcT   = xzT + 6291456;         // 3145728
    float* yT    = xcT + 3145728;         // 3145728
    float* xdT   = yT + 3145728;          // 44*8192 = 360448 (0-11 dtr, 12-27 B, 28-43 C)
    float* P     = xdT + 360448;          // 786432
    float* Hf    = P + 786432;            // 786432
    float* zsT   = xzT + DI * RT;         // z half, silu applied by gemm_xz epilogue

    fuse_w_kernel<<<768, 192, 0, stream>>>(in_proj_w, proj_w, proj_b,
                                           W2hi, W2lo, bias2, xdT);
    gemm_xz<<<dim3(128, 12), 256, 0, stream>>>(x, W2hi, W2lo, bias2, xzT);
    xproj_conv_gemm<<<dim3(128, 2), 512, 0, stream>>>(xzT, conv_w, conv_b,
                                                      xproj_w, xcT, xdT);
    scan_part1<<<dim3(16, 24, 8), 256, 0, stream>>>(xdT, xcT, dtproj_w, dtproj_b,
                                                    A_log, P, Hf);
    scan_part2<<<dim3(16, 24, 8), 256, 0, stream>>>(xdT, xcT, zsT, dtproj_w, dtproj_b,
                                                    P, Hf, A_log, Dp, yT);
    gemm_out<<<dim3(128, 3), 256, 0, stream>>>(yT, out_w, out);
}

// Round 8
// 202.205 us; speedup vs baseline: 1.2652x; 1.0384x over previous
//
#include <hip/hip_runtime.h>
#include <math.h>

// Problem constants (B=8, C=192, H=W=32)
#define BB 8
#define CC 192
#define LL 1024
#define RT 8192         // total rows = BB*LL
#define DI 384          // d_inner
#define DT_RANK 12
#define NS 16           // D_STATE
#define NSEG 16
#define SEGL 64

typedef __attribute__((ext_vector_type(8))) short bf16x8;   // 8 bf16 (4 VGPRs)
typedef __attribute__((ext_vector_type(4))) float f32x4;

// RNE float->bf16 and back, manual (no header dependency)
__device__ __forceinline__ unsigned short f2bf(float f) {
    unsigned u = __float_as_uint(f);
    unsigned r = (u + 0x7FFFu + ((u >> 16) & 1u)) >> 16;
    return (unsigned short)r;
}
__device__ __forceinline__ float bf2f(unsigned short h) {
    return __uint_as_float(((unsigned)h) << 16);
}

// ---------------------------------------------------------------------------
// DPP butterfly sum across a row of 16 lanes (lanes 16k..16k+15).
__device__ __forceinline__ float row_sum16(float v) {
    v += __int_as_float(__builtin_amdgcn_update_dpp(0, __float_as_int(v), 0x140, 0xF, 0xF, true));
    v += __int_as_float(__builtin_amdgcn_update_dpp(0, __float_as_int(v), 0x141, 0xF, 0xF, true));
    v += __int_as_float(__builtin_amdgcn_update_dpp(0, __float_as_int(v), 0x4E,  0xF, 0xF, true));
    v += __int_as_float(__builtin_amdgcn_update_dpp(0, __float_as_int(v), 0xB1,  0xF, 0xF, true));
    return v;
}

// ---------------------------------------------------------------------------
// K1: W2[j,c'] = sum_c in_proj_w[j,c]*proj_w[c,c'], emitted as SPLIT bf16
// planes W2hi/W2lo (w = hi + lo) for the MFMA gemm_xz. Also splits out_w
// into owhi/owlo planes (for the MFMA gemm_out; out_w is [c][d] row-major,
// fragments contiguous). bias2[j] = in_proj_w[j,:]·proj_b. Zero-inits xdT.
__global__ void fuse_w_kernel(const float* __restrict__ in_proj_w,
                              const float* __restrict__ proj_w,
                              const float* __restrict__ proj_b,
                              const float* __restrict__ out_w,
                              unsigned short* __restrict__ W2hi,
                              unsigned short* __restrict__ W2lo,
                              unsigned short* __restrict__ owhi,
                              unsigned short* __restrict__ owlo,
                              float* __restrict__ bias2,
                              float* __restrict__ xdT) {
    int j = blockIdx.x;
    int cp = threadIdx.x;
    int gtid = j * CC + cp;                       // 0..147455
    for (int i = gtid; i < 44 * RT; i += 768 * CC) xdT[i] = 0.f;
    if (j < DI) {
        float v = out_w[cp * DI + j];
        unsigned short h = f2bf(v);
        owhi[cp * DI + j] = h;
        owlo[cp * DI + j] = f2bf(v - bf2f(h));
    }
    __shared__ float wrow[CC];
    wrow[cp] = in_proj_w[j * CC + cp];
    __syncthreads();
    float acc = 0.f;
#pragma unroll 4
    for (int c = 0; c < CC; ++c) acc = fmaf(wrow[c], proj_w[c * CC + cp], acc);
    unsigned short h = f2bf(acc);
    W2hi[j * CC + cp] = h;
    W2lo[j * CC + cp] = f2bf(acc - bf2f(h));
    if (cp == 0) {
        float b = 0.f;
        for (int c = 0; c < CC; ++c) b = fmaf(wrow[c], proj_b[c], b);
        bias2[j] = b;
    }
}

// ---------------------------------------------------------------------------
// K2: xzT[j, row] = sum_c x[b,c,l]*W2[j,c] + bias2[j]  via split-bf16 MFMA.
// D = Whi*Xhi + Whi*Xlo + Wlo*Xhi (3x mfma_f32_16x16x32_bf16), ~2^-18 rel.
// Tile 64j x 64row, 4 waves; wave w owns j-slice jw=j0+w*16. x staged per
// 32-k step as hi/lo bf16 in B-fragment order. C/D mapping (HW-verified R7):
// col=lane&15, row=(lane>>4)*4+reg. grid (128,12), 256 thr, 8KB LDS.
__global__ __launch_bounds__(256) void gemm_xz(const float* __restrict__ x,
                                               const unsigned short* __restrict__ W2hi,
                                               const unsigned short* __restrict__ W2lo,
                                               const float* __restrict__ bias2,
                                               float* __restrict__ xzT) {
    __shared__ unsigned short xhi[2048];   // [kb][col][e] 4KB
    __shared__ unsigned short xlo[2048];
    int r0 = blockIdx.x * 64;
    int j0 = blockIdx.y * 64;
    int b  = r0 >> 10;
    int l0 = r0 & 1023;
    int tid = threadIdx.x;
    int lane = tid & 63;
    int wid = tid >> 6;          // wave id = staging kb
    int jw = j0 + wid * 16;
    const float* xb = x + b * CC * LL + l0 + lane;   // staging col = lane
    f32x4 z4 = {0.f, 0.f, 0.f, 0.f};
    f32x4 acc[4] = {z4, z4, z4, z4};
    int arow = jw + (lane & 15);           // A fragment row (j)
    int akb  = (lane >> 4) * 8;            // A fragment k sub-block
    for (int ks = 0; ks < 6; ++ks) {
        int k0 = ks * 32;
        // ---- stage x[k0+kb*8+e][l0+col] -> hi/lo bf16 in frag order
        float v[8];
#pragma unroll
        for (int e = 0; e < 8; ++e) v[e] = xb[(k0 + wid * 8 + e) * LL];
        union U8 { unsigned short u[8]; bf16x8 v8; } hv, lv;
#pragma unroll
        for (int e = 0; e < 8; ++e) {
            unsigned short h = f2bf(v[e]);
            hv.u[e] = h;
            lv.u[e] = f2bf(v[e] - bf2f(h));
        }
        *(bf16x8*)&xhi[(wid * 64 + lane) * 8] = hv.v8;
        *(bf16x8*)&xlo[(wid * 64 + lane) * 8] = lv.v8;
        __syncthreads();
        // ---- A fragments (hi/lo) for this k-step
        int aoff = arow * CC + k0 + akb;
        bf16x8 ah = *(const bf16x8*)&W2hi[aoff];
        bf16x8 al = *(const bf16x8*)&W2lo[aoff];
        // ---- 4 row sub-tiles x 3 split-mfma
#pragma unroll
        for (int rt = 0; rt < 4; ++rt) {
            int boff = ((lane >> 4) * 64 + rt * 16 + (lane & 15)) * 8;
            bf16x8 bh = *(const bf16x8*)&xhi[boff];
            bf16x8 bl = *(const bf16x8*)&xlo[boff];
            acc[rt] = __builtin_amdgcn_mfma_f32_16x16x32_bf16(ah, bh, acc[rt], 0, 0, 0);
            acc[rt] = __builtin_amdgcn_mfma_f32_16x16x32_bf16(ah, bl, acc[rt], 0, 0, 0);
            acc[rt] = __builtin_amdgcn_mfma_f32_16x16x32_bf16(al, bh, acc[rt], 0, 0, 0);
        }
        __syncthreads();
    }
    bool is_z = (j0 >= DI);
#pragma unroll
    for (int rt = 0; rt < 4; ++rt) {
        int rbase = r0 + rt * 16 + (lane & 15);
#pragma unroll
        for (int reg = 0; reg < 4; ++reg) {
            int j = jw + (lane >> 4) * 4 + reg;
            float o = acc[rt][reg] + bias2[j];
            if (is_z) o = __fdividef(o, 1.f + __expf(-o));
            xzT[j * RT + rbase] = o;
        }
    }
}

// ---------------------------------------------------------------------------
// K3: skinny GEMM with fused causal depthwise conv (k=4) + silu in staging.
// K-split: blockIdx.y picks channel range [y*192, y*192+192); staging and
// xzT reads done once per channel; partial sums via atomicAdd into
// pre-zeroed xdT (exactly 2 contributors -> deterministic). (R3-proven.)
__global__ __launch_bounds__(512) void xproj_conv_gemm(const float* __restrict__ xzT,
                                                       const float* __restrict__ conv_w,
                                                       const float* __restrict__ conv_b,
                                                       const float* __restrict__ aw,
                                                       float* __restrict__ xcT,
                                                       float* __restrict__ xdT) {
    __shared__ float Bs[32][64];
    int col0 = blockIdx.x * 64;
    int kbase = blockIdx.y * 192;
    int tid = threadIdx.x;
    int col = tid & 63, mg = tid >> 6;          // mg wave-uniform -> scalar A loads
    int mb = mg * 6;                             // rows mb..mb+5 (44..47 discarded)
    const float* ar[6];
#pragma unroll
    for (int m = 0; m < 6; ++m) ar[m] = aw + min(mb + m, 43) * DI + kbase;
    float acc[6] = {};
    int ks = tid >> 4, c4 = (tid & 15) * 4;
    bool atL0 = ((col0 & 1023) == 0) && (c4 == 0);   // conv zero-pad boundary
    for (int k0 = 0; k0 < 192; k0 += 32) {
        int dch = kbase + k0 + ks;
        const float* src = xzT + (size_t)dch * RT + col0 + c4;
        float4 cur = *(const float4*)src;
        float4 prev = make_float4(0.f, 0.f, 0.f, 0.f);
        if (!atL0) prev = *(const float4*)(src - 4);
        float4 w4 = *(const float4*)&conv_w[dch * 4];   // w0=x w1=y w2=z w3=w
        float bb = conv_b[dch];
        float v0 = bb + w4.w * cur.x + w4.z * prev.w + w4.y * prev.z + w4.x * prev.y;
        float v1 = bb + w4.w * cur.y + w4.z * cur.x  + w4.y * prev.w + w4.x * prev.z;
        float v2 = bb + w4.w * cur.z + w4.z * cur.y  + w4.y * cur.x  + w4.x * prev.w;
        float v3 = bb + w4.w * cur.w + w4.z * cur.z  + w4.y * cur.y  + w4.x * cur.x;
        float4 o;
        o.x = __fdividef(v0, 1.f + __expf(-v0));
        o.y = __fdividef(v1, 1.f + __expf(-v1));
        o.z = __fdividef(v2, 1.f + __expf(-v2));
        o.w = __fdividef(v3, 1.f + __expf(-v3));
        *(float4*)&Bs[ks][c4] = o;
        *(float4*)&xcT[(size_t)dch * RT + col0 + c4] = o;   // own channel range
        __syncthreads();
#pragma unroll
        for (int k = 0; k < 32; ++k) {
            float bv = Bs[k][col];
#pragma unroll
            for (int m = 0; m < 6; ++m)
                acc[m] = fmaf(ar[m][k0 + k], bv, acc[m]);
        }
        __syncthreads();
    }
#pragma unroll
    for (int m = 0; m < 6; ++m)
        if (mb + m < 44)
            atomicAdd(&xdT[(mb + m) * RT + col0 + col], acc[m]);
}

// ---------------------------------------------------------------------------
// K4a: per-segment scan from h=0; dt computed inline from dtr rows of xdT.
// Emits P = exp(a*sum(dt)) (== prod(dA)), Hf = final h.
// grid (16 seg, 24 dblk, 8 b), block 256.  (R1-proven version.)
__global__ __launch_bounds__(256) void scan_part1(const float* __restrict__ xdT,
                                                  const float* __restrict__ xcT,
                                                  const float* __restrict__ dtw,
                                                  const float* __restrict__ dtb,
                                                  const float* __restrict__ A_log,
                                                  float* __restrict__ P,
                                                  float* __restrict__ Hf) {
    __shared__ float dt_s[16][20], g_s[16][20], B_s[16][20];
    __shared__ float dtr_s[12][17];
    __shared__ float dtw_s[192];
    __shared__ float dtb_s[16];
    int seg = blockIdx.x, d0 = blockIdx.y * 16, b = blockIdx.z;
    int row0 = b * LL + seg * SEGL;
    int tid = threadIdx.x;
    int lane = tid & 63;
    int n = lane & 15;
    int dl = ((tid >> 6) << 2) | (lane >> 4);
    int tdd = tid >> 4, ti = tid & 15;
    if (tid < 192) dtw_s[tid] = dtw[d0 * DT_RANK + tid];
    if (tid < 16)  dtb_s[tid] = dtb[d0 + tid];
    float a = -__expf(A_log[(d0 + dl) * NS + n]);
    float h = 0.f, sdt = 0.f;
    for (int ch = 0; ch < 4; ++ch) {
        int r = row0 + ch * 16;
        float xv = xcT[(d0 + tdd) * RT + r + ti];
        B_s[tdd][ti] = xdT[(12 + tdd) * RT + r + ti];
        if (tid < 192) dtr_s[tid >> 4][ti] = xdT[(tid >> 4) * RT + r + ti];
        __syncthreads();     // staging ready (prev chunk's preloads done)
        float acc = dtb_s[tdd];
#pragma unroll
        for (int rr = 0; rr < DT_RANK; ++rr)
            acc = fmaf(dtr_s[rr][ti], dtw_s[tdd * DT_RANK + rr], acc);
        float dtv = fmaxf(acc, 0.f) + __logf(1.f + __expf(-fabsf(acc)));
        dt_s[tdd][ti] = dtv;
        g_s[tdd][ti]  = dtv * xv;
        __syncthreads();     // dt_s/g_s ready
        float dv[16], gb[16];
#pragma unroll
        for (int q = 0; q < 4; ++q) {
            float4 d4 = *(const float4*)&dt_s[dl][q * 4];   // broadcast within row
            float4 g4 = *(const float4*)&g_s[dl][q * 4];
            float4 b4 = *(const float4*)&B_s[n][q * 4];
            dv[q * 4 + 0] = d4.x; dv[q * 4 + 1] = d4.y;
            dv[q * 4 + 2] = d4.z; dv[q * 4 + 3] = d4.w;
            gb[q * 4 + 0] = g4.x * b4.x; gb[q * 4 + 1] = g4.y * b4.y;
            gb[q * 4 + 2] = g4.z * b4.z; gb[q * 4 + 3] = g4.w * b4.w;
        }
        __syncthreads();     // preload done -> next chunk may overwrite LDS
        float eh[16];
#pragma unroll
        for (int i = 0; i < 16; ++i) eh[i] = __expf(dv[i] * a);
#pragma unroll
        for (int i = 0; i < 16; ++i) {
            sdt += dv[i];
            h = fmaf(eh[i], h, gb[i]);
        }
    }
    int idx = ((seg * BB + b) * DI + d0 + dl) * NS + n;
    P[idx] = __expf(a * sdt);
    Hf[idx] = h;
}

// ---------------------------------------------------------------------------
// K4b: rescan each segment; h_init computed in-block by folding the earlier
// segments' (P,Hf) summaries. DPP row-of-16 butterfly for the n-reduction.
// (R1-proven version.)
__global__ __launch_bounds__(256) void scan_part2(const float* __restrict__ xdT,
                                                  const float* __restrict__ xcT,
                                                  const float* __restrict__ zsT,
                                                  const float* __restrict__ dtw,
                                                  const float* __restrict__ dtb,
                                                  const float* __restrict__ P,
                                                  const float* __restrict__ Hf,
                                                  const float* __restrict__ A_log,
                                                  const float* __restrict__ Dp,
                                                  float* __restrict__ yT) {
    __shared__ float dt_s[16][20], g_s[16][20], B_s[16][20], C_s[16][20];
    __shared__ float dtr_s[12][17];
    __shared__ float dtw_s[192];
    __shared__ float dtb_s[16];
    int seg = blockIdx.x, d0 = blockIdx.y * 16, b = blockIdx.z;
    int row0 = b * LL + seg * SEGL;
    int tid = threadIdx.x;
    int lane = tid & 63;
    int n = lane & 15;
    int dl = ((tid >> 6) << 2) | (lane >> 4);
    int d = d0 + dl;
    int tdd = tid >> 4, ti = tid & 15;
    if (tid < 192) dtw_s[tid] = dtw[d0 * DT_RANK + tid];
    if (tid < 16)  dtb_s[tid] = dtb[d0 + tid];
    float a = -__expf(A_log[d * NS + n]);
    float Dpd = Dp[d];
    // h_init: fold earlier segments' summaries (coalesced loads)
    float h = 0.f;
    for (int s = 0; s < seg; ++s) {
        int off = ((s * BB + b) * DI + d) * NS + n;
        h = fmaf(P[off], h, Hf[off]);
    }
    for (int ch = 0; ch < 4; ++ch) {
        int r = row0 + ch * 16;
        // epilogue operands for the (dl,n) writer role (L1/L2-resident)
        float xr = xcT[(size_t)d * RT + r + n];
        float zr = zsT[(size_t)d * RT + r + n];
        // staging role (tdd,ti)
        float xv = xcT[(d0 + tdd) * RT + r + ti];
        B_s[tdd][ti] = xdT[(12 + tdd) * RT + r + ti];
        C_s[tdd][ti] = xdT[(28 + tdd) * RT + r + ti];
        if (tid < 192) dtr_s[tid >> 4][ti] = xdT[(tid >> 4) * RT + r + ti];
        __syncthreads();     // staging ready
        float acc = dtb_s[tdd];
#pragma unroll
        for (int rr = 0; rr < DT_RANK; ++rr)
            acc = fmaf(dtr_s[rr][ti], dtw_s[tdd * DT_RANK + rr], acc);
        float dtv = fmaxf(acc, 0.f) + __logf(1.f + __expf(-fabsf(acc)));
        dt_s[tdd][ti] = dtv;
        g_s[tdd][ti]  = dtv * xv;
        __syncthreads();     // dt_s/g_s ready
        float dv[16], gb[16], cv[16];
#pragma unroll
        for (int q = 0; q < 4; ++q) {
            float4 d4 = *(const float4*)&dt_s[dl][q * 4];
            float4 g4 = *(const float4*)&g_s[dl][q * 4];
            float4 b4 = *(const float4*)&B_s[n][q * 4];
            float4 c4 = *(const float4*)&C_s[n][q * 4];
            dv[q * 4 + 0] = d4.x; dv[q * 4 + 1] = d4.y;
            dv[q * 4 + 2] = d4.z; dv[q * 4 + 3] = d4.w;
            gb[q * 4 + 0] = g4.x * b4.x; gb[q * 4 + 1] = g4.y * b4.y;
            gb[q * 4 + 2] = g4.z * b4.z; gb[q * 4 + 3] = g4.w * b4.w;
            cv[q * 4 + 0] = c4.x; cv[q * 4 + 1] = c4.y;
            cv[q * 4 + 2] = c4.z; cv[q * 4 + 3] = c4.w;
        }
        __syncthreads();     // preload done -> next chunk may overwrite LDS
        float eh[16];
#pragma unroll
        for (int i = 0; i < 16; ++i) eh[i] = __expf(dv[i] * a);
        float yacc = 0.f;
#pragma unroll
        for (int i = 0; i < 16; ++i) {
            h = fmaf(eh[i], h, gb[i]);
            float v = row_sum16(h * cv[i]);   // sum over n within the 16-lane row
            yacc = (n == i) ? v : yacc;       // lane n keeps step i==n
        }
        yT[(size_t)d * RT + r + n] = fmaf(xr, Dpd, yacc) * zr;
    }
}

// ---------------------------------------------------------------------------
// K5: out[b, c, l] = sum_d yT[d, row] * out_w[c, d]  via split-bf16 MFMA.
// R8: same proven pattern as gemm_xz (R7). Tile 64c x 64row, 4 waves; wave
// owns c-slice cw=c0+w*16; yT staged per 32-k step as hi/lo bf16 in
// B-fragment order; A-frags from owhi/owlo ([c][d] row-major, contiguous).
// 12 k-steps. grid (128, 3), 256 thr, 8KB LDS.
__global__ __launch_bounds__(256) void gemm_out(const float* __restrict__ yT,
                                                const unsigned short* __restrict__ owhi,
                                                const unsigned short* __restrict__ owlo,
                                                float* __restrict__ out) {
    __shared__ unsigned short yhi[2048];   // [kb][col][e] 4KB
    __shared__ unsigned short ylo[2048];
    int r0 = blockIdx.x * 64;
    int c0 = blockIdx.y * 64;
    int b  = r0 >> 10;
    int l0 = r0 & 1023;
    int tid = threadIdx.x;
    int lane = tid & 63;
    int wid = tid >> 6;          // wave id = staging kb
    int cw = c0 + wid * 16;
    const float* yb = yT + r0 + lane;      // staging col = lane
    f32x4 z4 = {0.f, 0.f, 0.f, 0.f};
    f32x4 acc[4] = {z4, z4, z4, z4};
    int arow = cw + (lane & 15);           // A fragment row (c)
    int akb  = (lane >> 4) * 8;            // A fragment k sub-block
    for (int ks = 0; ks < 12; ++ks) {
        int k0 = ks * 32;
        // ---- stage yT[k0+kb*8+e][r0+col] -> hi/lo bf16 in frag order
        float v[8];
#pragma unroll
        for (int e = 0; e < 8; ++e) v[e] = yb[(size_t)(k0 + wid * 8 + e) * RT];
        union U8 { unsigned short u[8]; bf16x8 v8; } hv, lv;
#pragma unroll
        for (int e = 0; e < 8; ++e) {
            unsigned short h = f2bf(v[e]);
            hv.u[e] = h;
            lv.u[e] = f2bf(v[e] - bf2f(h));
        }
        *(bf16x8*)&yhi[(wid * 64 + lane) * 8] = hv.v8;
        *(bf16x8*)&ylo[(wid * 64 + lane) * 8] = lv.v8;
        __syncthreads();
        // ---- A fragments (hi/lo)
        int aoff = arow * DI + k0 + akb;
        bf16x8 ah = *(const bf16x8*)&owhi[aoff];
        bf16x8 al = *(const bf16x8*)&owlo[aoff];
#pragma unroll
        for (int rt = 0; rt < 4; ++rt) {
            int boff = ((lane >> 4) * 64 + rt * 16 + (lane & 15)) * 8;
            bf16x8 bh = *(const bf16x8*)&yhi[boff];
            bf16x8 bl = *(const bf16x8*)&ylo[boff];
            acc[rt] = __builtin_amdgcn_mfma_f32_16x16x32_bf16(ah, bh, acc[rt], 0, 0, 0);
            acc[rt] = __builtin_amdgcn_mfma_f32_16x16x32_bf16(ah, bl, acc[rt], 0, 0, 0);
            acc[rt] = __builtin_amdgcn_mfma_f32_16x16x32_bf16(al, bh, acc[rt], 0, 0, 0);
        }
        __syncthreads();
    }
    float* ob = out + b * CC * LL;
#pragma unroll
    for (int rt = 0; rt < 4; ++rt) {
        int lbase = l0 + rt * 16 + (lane & 15);
#pragma unroll
        for (int reg = 0; reg < 4; ++reg) {
            int c = cw + (lane >> 4) * 4 + reg;
            ob[c * LL + lbase] = acc[rt][reg];
        }
    }
}

// ---------------------------------------------------------------------------
extern "C" void kernel_launch(void* const* d_in, const int* in_sizes, int n_in,
                              void* d_out, int out_size, void* d_ws, size_t ws_size,
                              hipStream_t stream) {
    const float* x         = (const float*)d_in[0];
    const float* proj_w    = (const float*)d_in[1];
    const float* proj_b    = (const float*)d_in[2];
    const float* in_proj_w = (const float*)d_in[3];
    const float* conv_w    = (const float*)d_in[4];
    const float* conv_b    = (const float*)d_in[5];
    const float* xproj_w   = (const float*)d_in[6];
    const float* dtproj_w  = (const float*)d_in[7];
    const float* dtproj_b  = (const float*)d_in[8];
    const float* A_log     = (const float*)d_in[9];
    const float* Dp        = (const float*)d_in[10];
    const float* out_w     = (const float*)d_in[11];
    float* out = (float*)d_out;

    float* ws    = (float*)d_ws;
    unsigned short* W2hi = (unsigned short*)ws;          // 147456 bf16 = 73728 f32 slots
    unsigned short* W2lo = (unsigned short*)(ws + 73728);
    float* bias2 = ws + 147456;           // 768
    float* xzT   = bias2 + 768;           // 768*8192 = 6291456 (x raw, z silu'd)
    float* xcT   = xzT + 6291456;         // 3145728
    float* yT    = xcT + 3145728;         // 3145728
    float* xdT   = yT + 3145728;          // 44*8192 = 360448 (0-11 dtr, 12-27 B, 28-43 C)
    float* P     = xdT + 360448;          // 786432
    float* Hf    = P + 786432;            // 786432
    unsigned short* owhi = (unsigned short*)(Hf + 786432);       // 73728 bf16 = 36864 f32
    unsigned short* owlo = (unsigned short*)(Hf + 786432 + 36864);
    float* zsT   = xzT + DI * RT;         // z half, silu applied by gemm_xz epilogue

    fuse_w_kernel<<<768, 192, 0, stream>>>(in_proj_w, proj_w, proj_b, out_w,
                                           W2hi, W2lo, owhi, owlo, bias2, xdT);
    gemm_xz<<<dim3(128, 12), 256, 0, stream>>>(x, W2hi, W2lo, bias2, xzT);
    xproj_conv_gemm<<<dim3(128, 2), 512, 0, stream>>>(xzT, conv_w, conv_b,
                                                      xproj_w, xcT, xdT);
    scan_part1<<<dim3(16, 24, 8), 256, 0, stream>>>(xdT, xcT, dtproj_w, dtproj_b,
                                                    A_log, P, Hf);
    scan_part2<<<dim3(16, 24, 8), 256, 0, stream>>>(xdT, xcT, zsT, dtproj_w, dtproj_b,
                                                    P, Hf, A_log, Dp, yT);
    gemm_out<<<dim3(128, 3), 256, 0, stream>>>(yT, owhi, owlo, out);
}